// Round 1
// baseline (1738.232 us; speedup 1.0000x reference)
//
#include <hip/hip_runtime.h>
#include <hip/hip_bf16.h>

// Problem: B=8, C=256, Cp=32, N=4096.
// o[b,c,m] = gamma * sum_n h[b,c,n] * softmax_n(f^T g)[n,m] + x[b,c,m]

// ---------------------------------------------------------------- f,g kernel
__global__ __launch_bounds__(256) void fg_kernel(
    const float* __restrict__ x, const float* __restrict__ Wq,
    const float* __restrict__ Wk, float* __restrict__ f, float* __restrict__ g)
{
    __shared__ float wq_s[256 * 32];   // [c][o]
    __shared__ float wk_s[256 * 32];
    const int tid = threadIdx.x;
    for (int idx = tid; idx < 32 * 256; idx += 256) {
        const int o = idx >> 8, c = idx & 255;
        wq_s[c * 32 + o] = Wq[idx];
        wk_s[c * 32 + o] = Wk[idx];
    }
    __syncthreads();
    const int b = blockIdx.y;
    const int n = (blockIdx.x << 8) + tid;
    const float* xp = x + ((size_t)b << 20) + n;
    float accf[32], accg[32];
#pragma unroll
    for (int o = 0; o < 32; o++) { accf[o] = 0.f; accg[o] = 0.f; }
    for (int c = 0; c < 256; c++) {
        const float xv = xp[(size_t)c << 12];
        const float4* wq4 = (const float4*)(wq_s + c * 32);
        const float4* wk4 = (const float4*)(wk_s + c * 32);
#pragma unroll
        for (int o4 = 0; o4 < 8; o4++) {
            const float4 a = wq4[o4], k = wk4[o4];
            accf[o4 * 4 + 0] += a.x * xv; accf[o4 * 4 + 1] += a.y * xv;
            accf[o4 * 4 + 2] += a.z * xv; accf[o4 * 4 + 3] += a.w * xv;
            accg[o4 * 4 + 0] += k.x * xv; accg[o4 * 4 + 1] += k.y * xv;
            accg[o4 * 4 + 2] += k.z * xv; accg[o4 * 4 + 3] += k.w * xv;
        }
    }
#pragma unroll
    for (int o = 0; o < 32; o++) {
        f[(((size_t)b * 32 + o) << 12) + n] = fmaxf(accf[o], 0.f);
        g[(((size_t)b * 32 + o) << 12) + n] = fmaxf(accg[o], 0.f);
    }
}

// ------------------------------------------------------------------ h kernel
__global__ __launch_bounds__(256) void h_kernel(
    const float* __restrict__ x, const float* __restrict__ Wv,
    float* __restrict__ h)
{
    __shared__ float wv_s[256 * 64];   // [c][o] tile of Wv rows o0..o0+63
    const int tid = threadIdx.x;
    const int o0 = blockIdx.y << 6;
    for (int idx = tid; idx < 64 * 256; idx += 256) {
        const int o = idx >> 8, c = idx & 255;
        wv_s[c * 64 + o] = Wv[(size_t)(o0 + o) * 256 + c];
    }
    __syncthreads();
    const int b = blockIdx.z;
    const int n = (blockIdx.x << 8) + tid;
    const float* xp = x + ((size_t)b << 20) + n;
    float acc[64];
#pragma unroll
    for (int o = 0; o < 64; o++) acc[o] = 0.f;
    for (int c = 0; c < 256; c++) {
        const float xv = xp[(size_t)c << 12];
        const float4* wv4 = (const float4*)(wv_s + c * 64);
#pragma unroll
        for (int o4 = 0; o4 < 16; o4++) {
            const float4 w = wv4[o4];
            acc[o4 * 4 + 0] += w.x * xv; acc[o4 * 4 + 1] += w.y * xv;
            acc[o4 * 4 + 2] += w.z * xv; acc[o4 * 4 + 3] += w.w * xv;
        }
    }
#pragma unroll
    for (int o = 0; o < 64; o++)
        h[(((size_t)b * 256 + o0 + o) << 12) + n] = fmaxf(acc[o], 0.f);
}

// ------------------------------------------------- fused flash-attn kernel
// Block: 256 threads handles (b, 64 output columns m0..m0+63).
// Pass 1: online (max,sum) of scores over all n.  Pass 2: recompute scores,
// p = exp(s-M)/L, O += h * p.  Never materializes the N x N score matrix.
__global__ __launch_bounds__(256) void attn_kernel(
    const float* __restrict__ f, const float* __restrict__ g,
    const float* __restrict__ h, const float* __restrict__ x,
    const float* __restrict__ gamma, float* __restrict__ out)
{
    __shared__ float f_s[32 * 36];     // [n'][c], row stride 36 (16B aligned)
    __shared__ float h_s[256 * 33];    // [c][n'], row stride 33
    __shared__ float p_s[32 * 68];     // [n'][j], row stride 68 (16B aligned)
    __shared__ float m_part[4][64];
    __shared__ float l_part[4][64];
    __shared__ float Mj[64], Lr[64];

    const int tid = threadIdx.x;
    const int b  = blockIdx.y;
    const int m0 = blockIdx.x << 6;
    const int j  = tid & 63;       // column within tile (pass-1/p roles)
    const int q  = tid >> 6;       // quarter 0..3
    const int nn  = tid & 31;      // loader roles
    const int cc0 = tid >> 5;      // 0..7

    const float* fb = f + ((size_t)b << 17);
    const float* gb = g + ((size_t)b << 17);
    const float* hb = h + ((size_t)b << 20);

    // g column j for this thread, in registers (reused in both passes)
    float greg[32];
#pragma unroll
    for (int c = 0; c < 32; c++) greg[c] = gb[((size_t)c << 12) + m0 + j];

    // ---------------- pass 1: per-column online max & sum-exp --------------
    float mt = -1e30f, lt = 0.f;
    for (int t = 0; t < 128; t++) {
        const int n0 = t << 5;
#pragma unroll
        for (int r = 0; r < 4; r++) {
            const int c = cc0 + (r << 3);
            f_s[nn * 36 + c] = fb[((size_t)c << 12) + n0 + nn];
        }
        __syncthreads();
#pragma unroll
        for (int k = 0; k < 8; k++) {
            const int np = (q << 3) + k;
            const float4* fr = (const float4*)(f_s + np * 36);
            float s = 0.f;
#pragma unroll
            for (int c4 = 0; c4 < 8; c4++) {
                const float4 fv = fr[c4];
                s += fv.x * greg[c4 * 4 + 0] + fv.y * greg[c4 * 4 + 1]
                   + fv.z * greg[c4 * 4 + 2] + fv.w * greg[c4 * 4 + 3];
            }
            const float nm = fmaxf(mt, s);
            lt = lt * __expf(mt - nm) + __expf(s - nm);
            mt = nm;
        }
        __syncthreads();
    }
    m_part[q][j] = mt;
    l_part[q][j] = lt;
    __syncthreads();
    if (tid < 64) {
        float M = m_part[0][tid];
#pragma unroll
        for (int qq = 1; qq < 4; qq++) M = fmaxf(M, m_part[qq][tid]);
        float L = 0.f;
#pragma unroll
        for (int qq = 0; qq < 4; qq++)
            L += l_part[qq][tid] * __expf(m_part[qq][tid] - M);
        Mj[tid] = M;
        Lr[tid] = 1.f / L;
    }
    __syncthreads();
    const float Mjv = Mj[j];
    const float Lrv = Lr[j];

    // ---------------- pass 2: O = h * p ------------------------------------
    const int cg = tid & 63;   // channel group (c = cg + 64*i)
    const int jg = tid >> 6;   // 16-column group
    float acc[4][16];
#pragma unroll
    for (int i = 0; i < 4; i++)
#pragma unroll
        for (int jj = 0; jj < 16; jj++) acc[i][jj] = 0.f;

    for (int t = 0; t < 128; t++) {
        const int n0 = t << 5;
#pragma unroll
        for (int r = 0; r < 4; r++) {
            const int c = cc0 + (r << 3);
            f_s[nn * 36 + c] = fb[((size_t)c << 12) + n0 + nn];
        }
#pragma unroll
        for (int r = 0; r < 8; r++) {      // h tile: 256x32, float4 loads
            const int idx = (r << 8) + tid;
            const int c = idx >> 3;
            const int n4 = (idx & 7) << 2;
            const float4 hv4 = *(const float4*)(hb + ((size_t)c << 12) + n0 + n4);
            h_s[c * 33 + n4 + 0] = hv4.x;
            h_s[c * 33 + n4 + 1] = hv4.y;
            h_s[c * 33 + n4 + 2] = hv4.z;
            h_s[c * 33 + n4 + 3] = hv4.w;
        }
        __syncthreads();
#pragma unroll
        for (int k = 0; k < 8; k++) {      // recompute scores -> p
            const int np = (q << 3) + k;
            const float4* fr = (const float4*)(f_s + np * 36);
            float s = 0.f;
#pragma unroll
            for (int c4 = 0; c4 < 8; c4++) {
                const float4 fv = fr[c4];
                s += fv.x * greg[c4 * 4 + 0] + fv.y * greg[c4 * 4 + 1]
                   + fv.z * greg[c4 * 4 + 2] + fv.w * greg[c4 * 4 + 3];
            }
            p_s[np * 68 + j] = __expf(s - Mjv) * Lrv;
        }
        __syncthreads();
        for (int np = 0; np < 32; np++) {  // O accumulate (FMA-bound)
            float pr[16];
            *(float4*)(pr + 0)  = *(const float4*)(p_s + np * 68 + (jg << 4) + 0);
            *(float4*)(pr + 4)  = *(const float4*)(p_s + np * 68 + (jg << 4) + 4);
            *(float4*)(pr + 8)  = *(const float4*)(p_s + np * 68 + (jg << 4) + 8);
            *(float4*)(pr + 12) = *(const float4*)(p_s + np * 68 + (jg << 4) + 12);
            float hv[4];
#pragma unroll
            for (int i = 0; i < 4; i++) hv[i] = h_s[(cg + (i << 6)) * 33 + np];
#pragma unroll
            for (int i = 0; i < 4; i++)
#pragma unroll
                for (int jj = 0; jj < 16; jj++)
                    acc[i][jj] += hv[i] * pr[jj];
        }
        __syncthreads();
    }

    // ---------------- epilogue: gamma * O + x ------------------------------
    const float gm = gamma[0];
#pragma unroll
    for (int i = 0; i < 4; i++) {
        const int c = cg + (i << 6);
        const size_t base = (((size_t)b * 256 + c) << 12) + m0 + (jg << 4);
#pragma unroll
        for (int jj4 = 0; jj4 < 4; jj4++) {
            const float4 xv = *(const float4*)(x + base + (jj4 << 2));
            float4 ov;
            ov.x = gm * acc[i][jj4 * 4 + 0] + xv.x;
            ov.y = gm * acc[i][jj4 * 4 + 1] + xv.y;
            ov.z = gm * acc[i][jj4 * 4 + 2] + xv.z;
            ov.w = gm * acc[i][jj4 * 4 + 3] + xv.w;
            *(float4*)(out + base + (jj4 << 2)) = ov;
        }
    }
}

// ------------------------------------------------------------------- launch
extern "C" void kernel_launch(void* const* d_in, const int* in_sizes, int n_in,
                              void* d_out, int out_size, void* d_ws, size_t ws_size,
                              hipStream_t stream) {
    const float* x     = (const float*)d_in[0];
    const float* Wq    = (const float*)d_in[1];
    const float* Wk    = (const float*)d_in[2];
    const float* Wv    = (const float*)d_in[3];
    const float* gamma = (const float*)d_in[4];
    float* out = (float*)d_out;

    float* f = (float*)d_ws;                 // 8*32*4096 floats (4 MB)
    float* g = f + (size_t)8 * 32 * 4096;    // 4 MB
    float* h = g + (size_t)8 * 32 * 4096;    // 8*256*4096 floats (33.6 MB)

    fg_kernel<<<dim3(16, 8), 256, 0, stream>>>(x, Wq, Wk, f, g);
    h_kernel<<<dim3(16, 4, 8), 256, 0, stream>>>(x, Wv, h);
    attn_kernel<<<dim3(64, 8), 256, 0, stream>>>(f, g, h, x, gamma, out);
}

// Round 2
// 561.659 us; speedup vs baseline: 3.0948x; 3.0948x over previous
//
#include <hip/hip_runtime.h>

// B=8, C=256, Cp=32, N=4096.
// o[b,c,m] = gamma * sum_n h[b,c,n] * softmax_n(f^T g)[n,m] + x[b,c,m]
// R2: bf16 MFMA for S = f^T g and O = h * P; exact 2-pass softmax in fp32.

typedef __attribute__((ext_vector_type(8))) short bf16x8;   // 8 bf16 (4 VGPRs)
typedef __attribute__((ext_vector_type(4))) float f32x4;

static __device__ __forceinline__ unsigned short f2bf(float x) {
    union { float f; unsigned u; } v; v.f = x;
    unsigned r = v.u + 0x7FFFu + ((v.u >> 16) & 1u);   // RNE
    return (unsigned short)(r >> 16);
}

// ------------------------------------------------------------- f,g producer
// f_t / g_t layout: [b][n][c] bf16 (c contiguous, 32 per n = 64B per thread)
__global__ __launch_bounds__(256) void fg_kernel(
    const float* __restrict__ x, const float* __restrict__ Wq,
    const float* __restrict__ Wk, unsigned short* __restrict__ f_t,
    unsigned short* __restrict__ g_t)
{
    __shared__ float wq_s[256 * 32];   // [c][o]
    __shared__ float wk_s[256 * 32];
    const int tid = threadIdx.x;
    for (int idx = tid; idx < 32 * 256; idx += 256) {
        const int o = idx >> 8, c = idx & 255;
        wq_s[c * 32 + o] = Wq[idx];
        wk_s[c * 32 + o] = Wk[idx];
    }
    __syncthreads();
    const int b = blockIdx.y;
    const int n = (blockIdx.x << 8) + tid;
    const float* xp = x + ((size_t)b << 20) + n;
    float accf[32], accg[32];
#pragma unroll
    for (int o = 0; o < 32; o++) { accf[o] = 0.f; accg[o] = 0.f; }
    for (int c = 0; c < 256; c++) {
        const float xv = xp[(size_t)c << 12];
        const float4* wq4 = (const float4*)(wq_s + c * 32);
        const float4* wk4 = (const float4*)(wk_s + c * 32);
#pragma unroll
        for (int o4 = 0; o4 < 8; o4++) {
            const float4 a = wq4[o4], k = wk4[o4];
            accf[o4 * 4 + 0] += a.x * xv; accf[o4 * 4 + 1] += a.y * xv;
            accf[o4 * 4 + 2] += a.z * xv; accf[o4 * 4 + 3] += a.w * xv;
            accg[o4 * 4 + 0] += k.x * xv; accg[o4 * 4 + 1] += k.y * xv;
            accg[o4 * 4 + 2] += k.z * xv; accg[o4 * 4 + 3] += k.w * xv;
        }
    }
    unsigned short of[32] __attribute__((aligned(16)));
    unsigned short og[32] __attribute__((aligned(16)));
#pragma unroll
    for (int o = 0; o < 32; o++) {
        of[o] = f2bf(fmaxf(accf[o], 0.f));
        og[o] = f2bf(fmaxf(accg[o], 0.f));
    }
    float4* fd = (float4*)(f_t + (((size_t)b << 12) + n) * 32);
    float4* gd = (float4*)(g_t + (((size_t)b << 12) + n) * 32);
#pragma unroll
    for (int k = 0; k < 4; k++) { fd[k] = ((float4*)of)[k]; gd[k] = ((float4*)og)[k]; }
}

// --------------------------------------------------------------- h producer
// h_bf layout: [b][c][n] bf16
__global__ __launch_bounds__(256) void h_kernel(
    const float* __restrict__ x, const float* __restrict__ Wv,
    unsigned short* __restrict__ h_bf)
{
    __shared__ float wv_s[256 * 64];   // [c][o] tile of Wv rows o0..o0+63
    const int tid = threadIdx.x;
    const int o0 = blockIdx.y << 6;
    for (int idx = tid; idx < 64 * 256; idx += 256) {
        const int o = idx >> 8, c = idx & 255;
        wv_s[c * 64 + o] = Wv[(size_t)(o0 + o) * 256 + c];
    }
    __syncthreads();
    const int b = blockIdx.z;
    const int n = (blockIdx.x << 8) + tid;
    const float* xp = x + ((size_t)b << 20) + n;
    float acc[64];
#pragma unroll
    for (int o = 0; o < 64; o++) acc[o] = 0.f;
    for (int c = 0; c < 256; c++) {
        const float xv = xp[(size_t)c << 12];
        const float4* wv4 = (const float4*)(wv_s + c * 64);
#pragma unroll
        for (int o4 = 0; o4 < 16; o4++) {
            const float4 w = wv4[o4];
            acc[o4 * 4 + 0] += w.x * xv; acc[o4 * 4 + 1] += w.y * xv;
            acc[o4 * 4 + 2] += w.z * xv; acc[o4 * 4 + 3] += w.w * xv;
        }
    }
#pragma unroll
    for (int o = 0; o < 64; o++)
        h_bf[(((size_t)b * 256 + o0 + o) << 12) + n] = f2bf(fmaxf(acc[o], 0.f));
}

// ------------------------------------------------------- MFMA attention
// Block = 256 thr (4 waves), handles (b, 32 m-columns). Exact 2-pass softmax.
// Pass 1: S via MFMA, online (max,sumexp) per m. Pass 2: recompute S,
// P=exp(s-M)/L -> LDS (C-layout -> B-layout), O += h*P via MFMA.
__global__ __launch_bounds__(256) void attn_kernel(
    const unsigned short* __restrict__ f_t, const unsigned short* __restrict__ g_t,
    const unsigned short* __restrict__ h_bf, const float* __restrict__ x,
    const float* __restrict__ gamma, float* __restrict__ out)
{
    __shared__ unsigned short p_s[32 * 72];   // [m][n], pitch 72 bf16
    __shared__ float red_m[128], red_l[128];  // [w][m(32)]
    __shared__ float sM[32], sLi[32];

    const int tid  = threadIdx.x;
    const int w    = tid >> 6;      // wave 0..3
    const int lane = tid & 63;
    const int q    = lane >> 4;     // quad 0..3
    const int r    = lane & 15;
    const int b    = blockIdx.y;
    const int m0   = blockIdx.x << 5;

    const size_t bN = (size_t)b << 12;          // b*4096 (n index base)
    const f32x4 zero = {0.f, 0.f, 0.f, 0.f};

    // g B-fragments for the block's two 16-m subtiles (live whole kernel)
    bf16x8 bg[2];
#pragma unroll
    for (int ms = 0; ms < 2; ms++)
        bg[ms] = *(const bf16x8*)(g_t + ((bN + m0 + ms * 16 + r) << 5) + (q << 3));

    // ---------------- pass 1: per-m (max, sumexp) over all n ---------------
    float mt[2] = {-1e30f, -1e30f}, lt[2] = {0.f, 0.f};
    for (int s = w; s < 256; s += 4) {
        const bf16x8 af = *(const bf16x8*)(f_t + ((bN + (s << 4) + r) << 5) + (q << 3));
        f32x4 sv[2];
        sv[0] = __builtin_amdgcn_mfma_f32_16x16x32_bf16(af, bg[0], zero, 0, 0, 0);
        sv[1] = __builtin_amdgcn_mfma_f32_16x16x32_bf16(af, bg[1], zero, 0, 0, 0);
#pragma unroll
        for (int ms = 0; ms < 2; ms++) {
            const float vm = fmaxf(fmaxf(sv[ms][0], sv[ms][1]), fmaxf(sv[ms][2], sv[ms][3]));
            const float nm = fmaxf(mt[ms], vm);
            float e = __expf(sv[ms][0] - nm) + __expf(sv[ms][1] - nm)
                    + __expf(sv[ms][2] - nm) + __expf(sv[ms][3] - nm);
            lt[ms] = lt[ms] * __expf(mt[ms] - nm) + e;
            mt[ms] = nm;
        }
    }
#pragma unroll
    for (int ms = 0; ms < 2; ms++) {
#pragma unroll
        for (int off = 16; off <= 32; off <<= 1) {
            const float mo = __shfl_xor(mt[ms], off);
            const float lo = __shfl_xor(lt[ms], off);
            const float nm = fmaxf(mt[ms], mo);
            lt[ms] = lt[ms] * __expf(mt[ms] - nm) + lo * __expf(mo - nm);
            mt[ms] = nm;
        }
        if (q == 0) {
            red_m[w * 32 + ms * 16 + r] = mt[ms];
            red_l[w * 32 + ms * 16 + r] = lt[ms];
        }
    }
    __syncthreads();
    if (tid < 32) {
        float M = red_m[tid];
#pragma unroll
        for (int ww = 1; ww < 4; ww++) M = fmaxf(M, red_m[ww * 32 + tid]);
        float L = 0.f;
#pragma unroll
        for (int ww = 0; ww < 4; ww++)
            L += red_l[ww * 32 + tid] * __expf(red_m[ww * 32 + tid] - M);
        sM[tid]  = M;
        sLi[tid] = 1.f / L;
    }
    __syncthreads();
    const float Mv[2] = {sM[r], sM[16 + r]};
    const float Lv[2] = {sLi[r], sLi[16 + r]};

    // ---------------- pass 2: O = h * P ------------------------------------
    f32x4 acc[4][2];
#pragma unroll
    for (int cs = 0; cs < 4; cs++)
#pragma unroll
        for (int ms = 0; ms < 2; ms++) acc[cs][ms] = zero;

    const size_t hbase = (size_t)b << 20;   // b*256*4096
    const int c0 = w << 6;                  // wave's channel range

    for (int t = 0; t < 64; t++) {
        const int n0 = t << 6;
        // this wave's 16-n slice of S
        const bf16x8 af = *(const bf16x8*)(f_t + ((bN + n0 + (w << 4) + r) << 5) + (q << 3));
        f32x4 sv[2];
        sv[0] = __builtin_amdgcn_mfma_f32_16x16x32_bf16(af, bg[0], zero, 0, 0, 0);
        sv[1] = __builtin_amdgcn_mfma_f32_16x16x32_bf16(af, bg[1], zero, 0, 0, 0);
        // P = exp(s-M)*Linv, C-layout -> LDS [m][n]
#pragma unroll
        for (int ms = 0; ms < 2; ms++) {
            unsigned p01 = (unsigned)f2bf(__expf(sv[ms][0] - Mv[ms]) * Lv[ms])
                         | ((unsigned)f2bf(__expf(sv[ms][1] - Mv[ms]) * Lv[ms]) << 16);
            unsigned p23 = (unsigned)f2bf(__expf(sv[ms][2] - Mv[ms]) * Lv[ms])
                         | ((unsigned)f2bf(__expf(sv[ms][3] - Mv[ms]) * Lv[ms]) << 16);
            uint2 pk; pk.x = p01; pk.y = p23;
            *(uint2*)(p_s + (ms * 16 + r) * 72 + (w << 4) + (q << 2)) = pk;
        }
        __syncthreads();
        // P B-fragments (2 K-chunks x 2 m-subtiles)
        bf16x8 bp[2][2];
#pragma unroll
        for (int ch = 0; ch < 2; ch++)
#pragma unroll
            for (int ms = 0; ms < 2; ms++)
                bp[ch][ms] = *(const bf16x8*)(p_s + (ms * 16 + r) * 72 + (ch << 5) + (q << 3));
        // O accumulation: A = h fragments straight from global (L2/L3 hit)
#pragma unroll
        for (int cs = 0; cs < 4; cs++) {
            const unsigned short* hp =
                h_bf + hbase + ((size_t)(c0 + cs * 16 + r) << 12) + n0 + (q << 3);
            const bf16x8 ah0 = *(const bf16x8*)(hp);
            const bf16x8 ah1 = *(const bf16x8*)(hp + 32);
            acc[cs][0] = __builtin_amdgcn_mfma_f32_16x16x32_bf16(ah0, bp[0][0], acc[cs][0], 0, 0, 0);
            acc[cs][1] = __builtin_amdgcn_mfma_f32_16x16x32_bf16(ah0, bp[0][1], acc[cs][1], 0, 0, 0);
            acc[cs][0] = __builtin_amdgcn_mfma_f32_16x16x32_bf16(ah1, bp[1][0], acc[cs][0], 0, 0, 0);
            acc[cs][1] = __builtin_amdgcn_mfma_f32_16x16x32_bf16(ah1, bp[1][1], acc[cs][1], 0, 0, 0);
        }
        __syncthreads();
    }

    // ---------------- epilogue: gamma * O + x ------------------------------
    const float gm = gamma[0];
#pragma unroll
    for (int cs = 0; cs < 4; cs++) {
#pragma unroll
        for (int ms = 0; ms < 2; ms++) {
#pragma unroll
            for (int reg = 0; reg < 4; reg++) {
                const int c = c0 + cs * 16 + q * 4 + reg;
                const size_t a = (((size_t)b * 256 + c) << 12) + m0 + ms * 16 + r;
                out[a] = gm * acc[cs][ms][reg] + x[a];
            }
        }
    }
}

// ------------------------------------------------------------------- launch
extern "C" void kernel_launch(void* const* d_in, const int* in_sizes, int n_in,
                              void* d_out, int out_size, void* d_ws, size_t ws_size,
                              hipStream_t stream) {
    const float* x     = (const float*)d_in[0];
    const float* Wq    = (const float*)d_in[1];
    const float* Wk    = (const float*)d_in[2];
    const float* Wv    = (const float*)d_in[3];
    const float* gamma = (const float*)d_in[4];
    float* out = (float*)d_out;

    unsigned short* f_t  = (unsigned short*)d_ws;                    // 2 MB
    unsigned short* g_t  = f_t + (size_t)8 * 4096 * 32;              // 2 MB
    unsigned short* h_bf = g_t + (size_t)8 * 4096 * 32;              // 16 MB

    fg_kernel<<<dim3(16, 8), 256, 0, stream>>>(x, Wq, Wk, f_t, g_t);
    h_kernel<<<dim3(16, 4, 8), 256, 0, stream>>>(x, Wv, h_bf);
    attn_kernel<<<dim3(128, 8), 256, 0, stream>>>(f_t, g_t, h_bf, x, gamma, out);
}

// Round 3
// 493.132 us; speedup vs baseline: 3.5249x; 1.1390x over previous
//
#include <hip/hip_runtime.h>

// B=8, C=256, Cp=32, N=4096.
// o[b,c,m] = gamma * sum_n h[b,c,n] * softmax_n(f^T g)[n,m] + x[b,c,m]
// R3: no pass-1 (Cauchy-Schwarz upper-bound max, cancels in normalization),
// deferred normalization, exp2 domain, perm-packed P, 1 barrier/iter.

typedef __attribute__((ext_vector_type(8))) short bf16x8;   // 8 bf16 (4 VGPRs)
typedef __attribute__((ext_vector_type(4))) float f32x4;

#define LOG2E 1.44269504088896f

static __device__ __forceinline__ unsigned short f2bf(float x) {
    union { float f; unsigned u; } v; v.f = x;
    unsigned r = v.u + 0x7FFFu + ((v.u >> 16) & 1u);   // RNE
    return (unsigned short)(r >> 16);
}
static __device__ __forceinline__ float bf2f(unsigned short u) {
    union { unsigned u; float f; } v; v.u = ((unsigned)u) << 16;
    return v.f;
}

// ------------------------------------------------------------- f,g producer
// f_t / g_t layout: [b][n][c] bf16. f is pre-scaled by log2(e).
// Also emits normg[b][n] = ||g_n||2 and maxnf[b] = max_n ||f_n||2 (scaled),
// both computed on the bf16-ROUNDED values so M-hat = maxnf*normg is a
// rigorous upper bound on any MFMA score (exp2 domain).
__global__ __launch_bounds__(256) void fg_kernel(
    const float* __restrict__ x, const float* __restrict__ Wq,
    const float* __restrict__ Wk, unsigned short* __restrict__ f_t,
    unsigned short* __restrict__ g_t, float* __restrict__ normg,
    unsigned* __restrict__ maxnf_u)
{
    __shared__ float wq_s[256 * 32];   // [c][o]
    __shared__ float wk_s[256 * 32];
    const int tid = threadIdx.x;
    for (int idx = tid; idx < 32 * 256; idx += 256) {
        const int o = idx >> 8, c = idx & 255;
        wq_s[c * 32 + o] = Wq[idx];
        wk_s[c * 32 + o] = Wk[idx];
    }
    __syncthreads();
    const int b = blockIdx.y;
    const int n = (blockIdx.x << 8) + tid;
    const float* xp = x + ((size_t)b << 20) + n;
    float accf[32], accg[32];
#pragma unroll
    for (int o = 0; o < 32; o++) { accf[o] = 0.f; accg[o] = 0.f; }
    for (int c = 0; c < 256; c++) {
        const float xv = xp[(size_t)c << 12];
        const float4* wq4 = (const float4*)(wq_s + c * 32);
        const float4* wk4 = (const float4*)(wk_s + c * 32);
#pragma unroll
        for (int o4 = 0; o4 < 8; o4++) {
            const float4 a = wq4[o4], k = wk4[o4];
            accf[o4 * 4 + 0] += a.x * xv; accf[o4 * 4 + 1] += a.y * xv;
            accf[o4 * 4 + 2] += a.z * xv; accf[o4 * 4 + 3] += a.w * xv;
            accg[o4 * 4 + 0] += k.x * xv; accg[o4 * 4 + 1] += k.y * xv;
            accg[o4 * 4 + 2] += k.z * xv; accg[o4 * 4 + 3] += k.w * xv;
        }
    }
    unsigned short of[32] __attribute__((aligned(16)));
    unsigned short og[32] __attribute__((aligned(16)));
    float nf2 = 0.f, ng2 = 0.f;
#pragma unroll
    for (int o = 0; o < 32; o++) {
        of[o] = f2bf(fmaxf(accf[o], 0.f) * LOG2E);
        og[o] = f2bf(fmaxf(accg[o], 0.f));
        const float fv = bf2f(of[o]);
        const float gv = bf2f(og[o]);
        nf2 += fv * fv;
        ng2 += gv * gv;
    }
    float4* fd = (float4*)(f_t + (((size_t)b << 12) + n) * 32);
    float4* gd = (float4*)(g_t + (((size_t)b << 12) + n) * 32);
#pragma unroll
    for (int k = 0; k < 4; k++) { fd[k] = ((float4*)of)[k]; gd[k] = ((float4*)og)[k]; }
    normg[((size_t)b << 12) + n] = sqrtf(ng2);
    float nf = sqrtf(nf2);
#pragma unroll
    for (int off = 1; off < 64; off <<= 1) nf = fmaxf(nf, __shfl_xor(nf, off));
    if ((tid & 63) == 0) atomicMax(maxnf_u + b, __float_as_uint(nf));
}

// --------------------------------------------------------------- h producer
__global__ __launch_bounds__(256) void h_kernel(
    const float* __restrict__ x, const float* __restrict__ Wv,
    unsigned short* __restrict__ h_bf)
{
    __shared__ float wv_s[256 * 64];   // [c][o] tile of Wv rows o0..o0+63
    const int tid = threadIdx.x;
    const int o0 = blockIdx.y << 6;
    for (int idx = tid; idx < 64 * 256; idx += 256) {
        const int o = idx >> 8, c = idx & 255;
        wv_s[c * 64 + o] = Wv[(size_t)(o0 + o) * 256 + c];
    }
    __syncthreads();
    const int b = blockIdx.z;
    const int n = (blockIdx.x << 8) + tid;
    const float* xp = x + ((size_t)b << 20) + n;
    float acc[64];
#pragma unroll
    for (int o = 0; o < 64; o++) acc[o] = 0.f;
    for (int c = 0; c < 256; c++) {
        const float xv = xp[(size_t)c << 12];
        const float4* wv4 = (const float4*)(wv_s + c * 64);
#pragma unroll
        for (int o4 = 0; o4 < 16; o4++) {
            const float4 w = wv4[o4];
            acc[o4 * 4 + 0] += w.x * xv; acc[o4 * 4 + 1] += w.y * xv;
            acc[o4 * 4 + 2] += w.z * xv; acc[o4 * 4 + 3] += w.w * xv;
        }
    }
#pragma unroll
    for (int o = 0; o < 64; o++)
        h_bf[(((size_t)b * 256 + o0 + o) << 12) + n] = f2bf(fmaxf(acc[o], 0.f));
}

// ------------------------------------------------------- MFMA attention
// Block = 256 thr (4 waves), (b, 32 m-cols). Single pass over n:
// S via MFMA (exp2 domain), P = exp2(s - Mhat) unnormalized -> LDS (bf16,
// truncation+v_perm pack), L accumulated in registers, PV via MFMA,
// epilogue scales by gamma/L. Double-buffered P: ONE barrier per n-tile.
__global__ __launch_bounds__(256, 4) void attn_kernel(
    const unsigned short* __restrict__ f_t, const unsigned short* __restrict__ g_t,
    const unsigned short* __restrict__ h_bf, const float* __restrict__ x,
    const float* __restrict__ gamma, const float* __restrict__ normg,
    const unsigned* __restrict__ maxnf_u, float* __restrict__ out)
{
    __shared__ unsigned short p_s[2][32 * 72];   // [buf][m][n], pitch 72 bf16
    __shared__ float red_l[4][32];
    __shared__ float sLi[32];

    const int tid  = threadIdx.x;
    const int w    = tid >> 6;      // wave 0..3
    const int lane = tid & 63;
    const int q    = lane >> 4;     // quad 0..3
    const int r    = lane & 15;
    const int b    = blockIdx.y;
    const int m0   = blockIdx.x << 5;

    const size_t bN = (size_t)b << 12;
    const f32x4 zero = {0.f, 0.f, 0.f, 0.f};

    // g B-fragments for the two 16-m subtiles (live whole kernel)
    bf16x8 bg[2];
#pragma unroll
    for (int ms = 0; ms < 2; ms++)
        bg[ms] = *(const bf16x8*)(g_t + ((bN + m0 + ms * 16 + r) << 5) + (q << 3));

    // upper bound on scores (exp2 domain); overshoot cancels via L
    const float mnf = __uint_as_float(maxnf_u[b]);
    const float Mh0 = mnf * normg[bN + m0 + r]      * 1.0002f;
    const float Mh1 = mnf * normg[bN + m0 + 16 + r] * 1.0002f;

    f32x4 acc[4][2];
#pragma unroll
    for (int cs = 0; cs < 4; cs++)
#pragma unroll
        for (int ms = 0; ms < 2; ms++) acc[cs][ms] = zero;
    float lt0 = 0.f, lt1 = 0.f;

    const size_t hbase = (size_t)b << 20;
    const int c0 = w << 6;

    for (int t = 0; t < 64; t++) {
        const int n0 = t << 6;
        unsigned short* pb = p_s[t & 1];
        // S for this wave's 16-n slice
        const bf16x8 af = *(const bf16x8*)(f_t + ((bN + n0 + (w << 4) + r) << 5) + (q << 3));
        const f32x4 sv0 = __builtin_amdgcn_mfma_f32_16x16x32_bf16(af, bg[0], zero, 0, 0, 0);
        const f32x4 sv1 = __builtin_amdgcn_mfma_f32_16x16x32_bf16(af, bg[1], zero, 0, 0, 0);
        // P = exp2(s - Mhat): fp32 for L, truncate+perm-pack to bf16 for LDS
        {
            const float e0 = __builtin_amdgcn_exp2f(sv0[0] - Mh0);
            const float e1 = __builtin_amdgcn_exp2f(sv0[1] - Mh0);
            const float e2 = __builtin_amdgcn_exp2f(sv0[2] - Mh0);
            const float e3 = __builtin_amdgcn_exp2f(sv0[3] - Mh0);
            lt0 += (e0 + e1) + (e2 + e3);
            uint2 pk;
            pk.x = __builtin_amdgcn_perm(__float_as_uint(e1), __float_as_uint(e0), 0x07060302u);
            pk.y = __builtin_amdgcn_perm(__float_as_uint(e3), __float_as_uint(e2), 0x07060302u);
            *(uint2*)(pb + r * 72 + (w << 4) + (q << 2)) = pk;
        }
        {
            const float e0 = __builtin_amdgcn_exp2f(sv1[0] - Mh1);
            const float e1 = __builtin_amdgcn_exp2f(sv1[1] - Mh1);
            const float e2 = __builtin_amdgcn_exp2f(sv1[2] - Mh1);
            const float e3 = __builtin_amdgcn_exp2f(sv1[3] - Mh1);
            lt1 += (e0 + e1) + (e2 + e3);
            uint2 pk;
            pk.x = __builtin_amdgcn_perm(__float_as_uint(e1), __float_as_uint(e0), 0x07060302u);
            pk.y = __builtin_amdgcn_perm(__float_as_uint(e3), __float_as_uint(e2), 0x07060302u);
            *(uint2*)(pb + (16 + r) * 72 + (w << 4) + (q << 2)) = pk;
        }
        // prefetch h A-fragments (no LDS dependence -> overlaps barrier)
        bf16x8 ah[8];
#pragma unroll
        for (int cs = 0; cs < 4; cs++) {
            const unsigned short* hp =
                h_bf + hbase + ((size_t)(c0 + cs * 16 + r) << 12) + n0 + (q << 3);
            ah[cs * 2]     = *(const bf16x8*)(hp);
            ah[cs * 2 + 1] = *(const bf16x8*)(hp + 32);
        }
        __syncthreads();
        bf16x8 bp[2][2];
#pragma unroll
        for (int ch = 0; ch < 2; ch++)
#pragma unroll
            for (int ms = 0; ms < 2; ms++)
                bp[ch][ms] = *(const bf16x8*)(pb + (ms * 16 + r) * 72 + (ch << 5) + (q << 3));
#pragma unroll
        for (int cs = 0; cs < 4; cs++) {
            acc[cs][0] = __builtin_amdgcn_mfma_f32_16x16x32_bf16(ah[cs * 2],     bp[0][0], acc[cs][0], 0, 0, 0);
            acc[cs][1] = __builtin_amdgcn_mfma_f32_16x16x32_bf16(ah[cs * 2],     bp[0][1], acc[cs][1], 0, 0, 0);
            acc[cs][0] = __builtin_amdgcn_mfma_f32_16x16x32_bf16(ah[cs * 2 + 1], bp[1][0], acc[cs][0], 0, 0, 0);
            acc[cs][1] = __builtin_amdgcn_mfma_f32_16x16x32_bf16(ah[cs * 2 + 1], bp[1][1], acc[cs][1], 0, 0, 0);
        }
    }

    // ---------------- L reduction (once) -----------------------------------
    lt0 += __shfl_xor(lt0, 16); lt0 += __shfl_xor(lt0, 32);
    lt1 += __shfl_xor(lt1, 16); lt1 += __shfl_xor(lt1, 32);
    __syncthreads();
    if (q == 0) { red_l[w][r] = lt0; red_l[w][16 + r] = lt1; }
    __syncthreads();
    if (tid < 32)
        sLi[tid] = 1.f / (red_l[0][tid] + red_l[1][tid] + red_l[2][tid] + red_l[3][tid]);
    __syncthreads();

    // ---------------- epilogue: (gamma/L) * O + x --------------------------
    const float gm = gamma[0];
    const float gl0 = gm * sLi[r];
    const float gl1 = gm * sLi[16 + r];
#pragma unroll
    for (int cs = 0; cs < 4; cs++) {
#pragma unroll
        for (int ms = 0; ms < 2; ms++) {
            const float gl = ms ? gl1 : gl0;
#pragma unroll
            for (int reg = 0; reg < 4; reg++) {
                const int c = c0 + cs * 16 + q * 4 + reg;
                const size_t a = (((size_t)b * 256 + c) << 12) + m0 + ms * 16 + r;
                out[a] = gl * acc[cs][ms][reg] + x[a];
            }
        }
    }
}

// ------------------------------------------------------------------- launch
extern "C" void kernel_launch(void* const* d_in, const int* in_sizes, int n_in,
                              void* d_out, int out_size, void* d_ws, size_t ws_size,
                              hipStream_t stream) {
    const float* x     = (const float*)d_in[0];
    const float* Wq    = (const float*)d_in[1];
    const float* Wk    = (const float*)d_in[2];
    const float* Wv    = (const float*)d_in[3];
    const float* gamma = (const float*)d_in[4];
    float* out = (float*)d_out;

    char* ws = (char*)d_ws;
    unsigned short* f_t  = (unsigned short*)ws;                       // 2 MB
    unsigned short* g_t  = (unsigned short*)(ws + (2u << 20));        // 2 MB
    unsigned short* h_bf = (unsigned short*)(ws + (4u << 20));        // 16 MB
    float*          ng   = (float*)(ws + (20u << 20));                // 128 KB
    unsigned*       mnf  = (unsigned*)(ws + (20u << 20) + (1u << 17)); // 32 B

    hipMemsetAsync(mnf, 0, 8 * sizeof(unsigned), stream);
    fg_kernel<<<dim3(16, 8), 256, 0, stream>>>(x, Wq, Wk, f_t, g_t, ng, mnf);
    h_kernel<<<dim3(16, 4, 8), 256, 0, stream>>>(x, Wv, h_bf);
    attn_kernel<<<dim3(128, 8), 256, 0, stream>>>(f_t, g_t, h_bf, x, gamma, ng, mnf, out);
}

// Round 4
// 256.122 us; speedup vs baseline: 6.7867x; 1.9254x over previous
//
#include <hip/hip_runtime.h>

// B=8, C=256, Cp=32, N=4096.
// o[b,c,m] = gamma * sum_n h[b,c,n] * softmax_n(f^T g)[n,m] + x[b,c,m]
// R4: fused MFMA producer (f,g,h from one x-staging); attn m-tile 64
// (halves h L2 traffic), af software pipeline, ah issued early.

typedef __attribute__((ext_vector_type(8))) short bf16x8;    // 8 bf16
typedef __attribute__((ext_vector_type(4))) float f32x4;
typedef __attribute__((ext_vector_type(4))) unsigned short us4;

#define LOG2E 1.44269504088896f

static __device__ __forceinline__ unsigned short f2bf(float x) {
    union { float f; unsigned u; } v; v.f = x;
    unsigned r = v.u + 0x7FFFu + ((v.u >> 16) & 1u);   // RNE
    return (unsigned short)(r >> 16);
}
static __device__ __forceinline__ float bf2f(unsigned short u) {
    union { unsigned u; float f; } v; v.u = ((unsigned)u) << 16;
    return v.f;
}

// ------------------------------------------------ weight convert (fp32->bf16)
// wq rows pre-scaled by log2(e) (relu commutes with positive scale).
__global__ __launch_bounds__(256) void wconv_kernel(
    const float* __restrict__ Wq, const float* __restrict__ Wk,
    const float* __restrict__ Wv, unsigned short* __restrict__ wq,
    unsigned short* __restrict__ wk, unsigned short* __restrict__ wv)
{
    const int i = blockIdx.x * 256 + threadIdx.x;   // 320 blocks -> 81920
    if (i < 8192)            wq[i] = f2bf(Wq[i] * LOG2E);
    else if (i < 16384)      wk[i - 8192] = f2bf(Wk[i - 8192]);
    else                     wv[i - 16384] = f2bf(Wv[i - 16384]);
}

// --------------------------------------------------- fused f,g,h producer
// Block = 256 thr (4 waves) handles (b, 64 n). Stage x[c=256][n=64] -> LDS
// transposed [n][c] bf16, then MFMA:
//   h = relu(Wv x)  (per-wave 64-c range, A=wv rows from global/L2)
//   f = relu(Wq*L2E x), g = relu(Wk x)  (wave w computes its 16-n slice)
// Emits f_t/g_t [b][n][32c] bf16, h_bf [b][c][n] bf16, normg, maxnf.
#define XPITCH 264
__global__ __launch_bounds__(256, 2) void producer_kernel(
    const float* __restrict__ x, const unsigned short* __restrict__ wq,
    const unsigned short* __restrict__ wk, const unsigned short* __restrict__ wv,
    unsigned short* __restrict__ f_t, unsigned short* __restrict__ g_t,
    unsigned short* __restrict__ h_bf, float* __restrict__ normg,
    unsigned* __restrict__ maxnf_u)
{
    __shared__ unsigned short x_s[64 * XPITCH];      // [n][c], 33.8 KB
    __shared__ unsigned short fg_s[4 * 2 * 512];     // per-wave f,g repack, 8 KB

    const int tid  = threadIdx.x;
    const int w    = tid >> 6;
    const int lane = tid & 63;
    const int q    = lane >> 4;
    const int r    = lane & 15;
    const int b    = blockIdx.y;
    const int n0   = blockIdx.x << 6;
    const size_t bN = (size_t)b << 12;
    const f32x4 zero = {0.f, 0.f, 0.f, 0.f};

    // ---- stage x tile (transpose fp32 [c][n] -> bf16 LDS [n][c]) ----------
#pragma unroll
    for (int jj = 0; jj < 4; jj++) {
        const int task = jj * 256 + tid;       // 1024 tasks: (c-quad, n-quad)
        const int n4 = task & 15;              // n-quad 0..15
        const int c4 = task >> 4;              // c-quad 0..63
        float va[4][4];
#pragma unroll
        for (int i = 0; i < 4; i++) {
            const float4 v = ((const float4*)(x + ((size_t)b << 20)
                              + (size_t)(c4 * 4 + i) * 4096 + n0))[n4];
            va[i][0] = v.x; va[i][1] = v.y; va[i][2] = v.z; va[i][3] = v.w;
        }
#pragma unroll
        for (int i = 0; i < 4; i++) {
            us4 t;
            t.x = f2bf(va[0][i]); t.y = f2bf(va[1][i]);
            t.z = f2bf(va[2][i]); t.w = f2bf(va[3][i]);
            *(us4*)(x_s + (n4 * 4 + i) * XPITCH + c4 * 4) = t;
        }
    }
    __syncthreads();

    // ---- MFMA: h (4 cs x 4 ns), f,g (2 ms each, ns == w) ------------------
    f32x4 acch[4][4];
    f32x4 accf[2], accg[2];
#pragma unroll
    for (int cs = 0; cs < 4; cs++)
#pragma unroll
        for (int ns = 0; ns < 4; ns++) acch[cs][ns] = zero;
    accf[0] = accf[1] = accg[0] = accg[1] = zero;

    for (int ks = 0; ks < 8; ks++) {
        const int kof = ks * 32 + q * 8;
        bf16x8 av[4], aq[2], ak[2];
#pragma unroll
        for (int cs = 0; cs < 4; cs++)
            av[cs] = *(const bf16x8*)(wv + (size_t)(w * 64 + cs * 16 + r) * 256 + kof);
#pragma unroll
        for (int ms = 0; ms < 2; ms++) {
            aq[ms] = *(const bf16x8*)(wq + (size_t)(ms * 16 + r) * 256 + kof);
            ak[ms] = *(const bf16x8*)(wk + (size_t)(ms * 16 + r) * 256 + kof);
        }
#pragma unroll
        for (int ns = 0; ns < 4; ns++) {
            const bf16x8 bx = *(const bf16x8*)(x_s + (ns * 16 + r) * XPITCH + kof);
#pragma unroll
            for (int cs = 0; cs < 4; cs++)
                acch[cs][ns] = __builtin_amdgcn_mfma_f32_16x16x32_bf16(av[cs], bx, acch[cs][ns], 0, 0, 0);
            if (ns == w) {
#pragma unroll
                for (int ms = 0; ms < 2; ms++) {
                    accf[ms] = __builtin_amdgcn_mfma_f32_16x16x32_bf16(aq[ms], bx, accf[ms], 0, 0, 0);
                    accg[ms] = __builtin_amdgcn_mfma_f32_16x16x32_bf16(ak[ms], bx, accg[ms], 0, 0, 0);
                }
            }
        }
    }

    // ---- h store: D[c][n] (c = q*4+reg rows, n = r col) -------------------
#pragma unroll
    for (int cs = 0; cs < 4; cs++)
#pragma unroll
        for (int ns = 0; ns < 4; ns++)
#pragma unroll
            for (int reg = 0; reg < 4; reg++)
                h_bf[(((size_t)b * 256 + w * 64 + cs * 16 + q * 4 + reg) << 12)
                     + n0 + ns * 16 + r] = f2bf(fmaxf(acch[cs][ns][reg], 0.f));

    // ---- f,g: relu+bf16 -> per-wave LDS [n(16)][c'(32)] -> vector store ---
    unsigned short* lf = fg_s + w * 1024;
    unsigned short* lg = lf + 512;
#pragma unroll
    for (int ms = 0; ms < 2; ms++)
#pragma unroll
        for (int reg = 0; reg < 4; reg++) {
            lf[r * 32 + ms * 16 + q * 4 + reg] = f2bf(fmaxf(accf[ms][reg], 0.f));
            lg[r * 32 + ms * 16 + q * 4 + reg] = f2bf(fmaxf(accg[ms][reg], 0.f));
        }
    // wave-private region: dependency-tracked LDS, no barrier needed
    const bf16x8 ffrag = *(const bf16x8*)(lf + r * 32 + q * 8);
    const bf16x8 gfrag = *(const bf16x8*)(lg + r * 32 + q * 8);
    *(bf16x8*)(f_t + ((bN + n0 + w * 16 + r) << 5) + q * 8) = ffrag;
    *(bf16x8*)(g_t + ((bN + n0 + w * 16 + r) << 5) + q * 8) = gfrag;

    float nf2 = 0.f, ng2 = 0.f;
#pragma unroll
    for (int i = 0; i < 8; i++) {
        const float fv = bf2f(((unsigned short*)&ffrag)[i]);
        const float gv = bf2f(((unsigned short*)&gfrag)[i]);
        nf2 += fv * fv; ng2 += gv * gv;
    }
    nf2 += __shfl_xor(nf2, 16); nf2 += __shfl_xor(nf2, 32);
    ng2 += __shfl_xor(ng2, 16); ng2 += __shfl_xor(ng2, 32);
    if (q == 0) normg[bN + n0 + w * 16 + r] = sqrtf(ng2);
    float nf = sqrtf(nf2);
#pragma unroll
    for (int off = 1; off < 16; off <<= 1) nf = fmaxf(nf, __shfl_xor(nf, off));
    if (lane == 0) atomicMax(maxnf_u + b, __float_as_uint(nf));
}

// ------------------------------------------------------- MFMA attention
// Block = 256 thr (4 waves), (b, 64 m-cols). Single pass over n, deferred
// normalization (Cauchy-Schwarz bound), double-buffered P, af pipelined.
__global__ __launch_bounds__(256, 2) void attn_kernel(
    const unsigned short* __restrict__ f_t, const unsigned short* __restrict__ g_t,
    const unsigned short* __restrict__ h_bf, const float* __restrict__ x,
    const float* __restrict__ gamma, const float* __restrict__ normg,
    const unsigned* __restrict__ maxnf_u, float* __restrict__ out)
{
    __shared__ unsigned short p_s[2][64 * 72];   // [buf][m][n], pitch 72
    __shared__ float red_l[4][64];
    __shared__ float sLi[64];

    const int tid  = threadIdx.x;
    const int w    = tid >> 6;
    const int lane = tid & 63;
    const int q    = lane >> 4;
    const int r    = lane & 15;
    const int b    = blockIdx.y;
    const int m0   = blockIdx.x << 6;

    const size_t bN = (size_t)b << 12;
    const size_t hbase = (size_t)b << 20;
    const int c0 = w << 6;
    const f32x4 zero = {0.f, 0.f, 0.f, 0.f};

    bf16x8 bg[4];
    float Mh[4];
    const float mnf = __uint_as_float(maxnf_u[b]);
#pragma unroll
    for (int ms = 0; ms < 4; ms++) {
        bg[ms] = *(const bf16x8*)(g_t + ((bN + m0 + ms * 16 + r) << 5) + (q << 3));
        Mh[ms] = mnf * normg[bN + m0 + ms * 16 + r] * 1.0002f;
    }

    f32x4 acc[4][4];
#pragma unroll
    for (int cs = 0; cs < 4; cs++)
#pragma unroll
        for (int ms = 0; ms < 4; ms++) acc[cs][ms] = zero;
    float lt[4] = {0.f, 0.f, 0.f, 0.f};

    bf16x8 af = *(const bf16x8*)(f_t + ((bN + (w << 4) + r) << 5) + (q << 3));

    for (int t = 0; t < 64; t++) {
        const int n0 = t << 6;
        unsigned short* pb = p_s[t & 1];
        // issue h loads first: they drain at the barrier, hidden under exp/pack
        bf16x8 ah[8];
#pragma unroll
        for (int cs = 0; cs < 4; cs++) {
            const unsigned short* hp =
                h_bf + hbase + ((size_t)(c0 + cs * 16 + r) << 12) + n0 + (q << 3);
            ah[cs * 2]     = *(const bf16x8*)(hp);
            ah[cs * 2 + 1] = *(const bf16x8*)(hp + 32);
        }
        f32x4 sv[4];
#pragma unroll
        for (int ms = 0; ms < 4; ms++)
            sv[ms] = __builtin_amdgcn_mfma_f32_16x16x32_bf16(af, bg[ms], zero, 0, 0, 0);
        // prefetch next f fragment (in flight across exp/pack + barrier)
        if (t < 63)
            af = *(const bf16x8*)(f_t + ((bN + ((t + 1) << 6) + (w << 4) + r) << 5) + (q << 3));
#pragma unroll
        for (int ms = 0; ms < 4; ms++) {
            const float e0 = __builtin_amdgcn_exp2f(sv[ms][0] - Mh[ms]);
            const float e1 = __builtin_amdgcn_exp2f(sv[ms][1] - Mh[ms]);
            const float e2 = __builtin_amdgcn_exp2f(sv[ms][2] - Mh[ms]);
            const float e3 = __builtin_amdgcn_exp2f(sv[ms][3] - Mh[ms]);
            lt[ms] += (e0 + e1) + (e2 + e3);
            uint2 pk;
            pk.x = __builtin_amdgcn_perm(__float_as_uint(e1), __float_as_uint(e0), 0x07060302u);
            pk.y = __builtin_amdgcn_perm(__float_as_uint(e3), __float_as_uint(e2), 0x07060302u);
            *(uint2*)(pb + (ms * 16 + r) * 72 + (w << 4) + (q << 2)) = pk;
        }
        __syncthreads();
#pragma unroll
        for (int ch = 0; ch < 2; ch++) {
            bf16x8 bp[4];
#pragma unroll
            for (int ms = 0; ms < 4; ms++)
                bp[ms] = *(const bf16x8*)(pb + (ms * 16 + r) * 72 + (ch << 5) + (q << 3));
#pragma unroll
            for (int cs = 0; cs < 4; cs++)
#pragma unroll
                for (int ms = 0; ms < 4; ms++)
                    acc[cs][ms] = __builtin_amdgcn_mfma_f32_16x16x32_bf16(
                        ah[cs * 2 + ch], bp[ms], acc[cs][ms], 0, 0, 0);
        }
    }

    // ---------------- L reduction ------------------------------------------
#pragma unroll
    for (int ms = 0; ms < 4; ms++) {
        lt[ms] += __shfl_xor(lt[ms], 16);
        lt[ms] += __shfl_xor(lt[ms], 32);
    }
    __syncthreads();
    if (q == 0)
#pragma unroll
        for (int ms = 0; ms < 4; ms++) red_l[w][ms * 16 + r] = lt[ms];
    __syncthreads();
    if (tid < 64)
        sLi[tid] = 1.f / (red_l[0][tid] + red_l[1][tid] + red_l[2][tid] + red_l[3][tid]);
    __syncthreads();

    // ---------------- epilogue: (gamma/L) * O + x --------------------------
    const float gm = gamma[0];
#pragma unroll
    for (int cs = 0; cs < 4; cs++) {
#pragma unroll
        for (int ms = 0; ms < 4; ms++) {
            const float gl = gm * sLi[ms * 16 + r];
#pragma unroll
            for (int reg = 0; reg < 4; reg++) {
                const int c = c0 + cs * 16 + q * 4 + reg;
                const size_t a = (((size_t)b * 256 + c) << 12) + m0 + ms * 16 + r;
                out[a] = gl * acc[cs][ms][reg] + x[a];
            }
        }
    }
}

// ------------------------------------------------------------------- launch
extern "C" void kernel_launch(void* const* d_in, const int* in_sizes, int n_in,
                              void* d_out, int out_size, void* d_ws, size_t ws_size,
                              hipStream_t stream) {
    const float* x     = (const float*)d_in[0];
    const float* Wq    = (const float*)d_in[1];
    const float* Wk    = (const float*)d_in[2];
    const float* Wv    = (const float*)d_in[3];
    const float* gamma = (const float*)d_in[4];
    float* out = (float*)d_out;

    char* ws = (char*)d_ws;
    unsigned short* f_t  = (unsigned short*)ws;                        // 2 MB
    unsigned short* g_t  = (unsigned short*)(ws + (2u << 20));         // 2 MB
    unsigned short* h_bf = (unsigned short*)(ws + (4u << 20));         // 16 MB
    float*          ng   = (float*)(ws + (20u << 20));                 // 128 KB
    unsigned*       mnf  = (unsigned*)(ws + (20u << 20) + (1u << 17)); // 32 B
    unsigned short* wq   = (unsigned short*)(ws + (21u << 20));        // 16 KB
    unsigned short* wk   = wq + 8192;                                  // 16 KB
    unsigned short* wv   = wk + 8192;                                  // 128 KB

    hipMemsetAsync(mnf, 0, 8 * sizeof(unsigned), stream);
    wconv_kernel<<<dim3(320), 256, 0, stream>>>(Wq, Wk, Wv, wq, wk, wv);
    producer_kernel<<<dim3(64, 8), 256, 0, stream>>>(x, wq, wk, wv, f_t, g_t, h_bf, ng, mnf);
    attn_kernel<<<dim3(64, 8), 256, 0, stream>>>(f_t, g_t, h_bf, x, gamma, ng, mnf, out);
}